// Round 1
// baseline (454.334 us; speedup 1.0000x reference)
//
#include <hip/hip_runtime.h>
#include <math.h>

#define TPB 256
static constexpr int N0  = 64;   // nodes per graph
static constexpr int H   = 128;  // hidden
static constexpr int XLD = 132;  // LDS row stride for feature tiles (16B aligned, bank-skewed)
static constexpr int ALD = 65;   // LDS row stride for adjacency (conflict-free column access)

struct alignas(16) Shm {
  float adjS[N0 * ALD];   // 16640 B  current adjacency (raw, no self loops)
  float Xs[N0 * XLD];     // 33792 B  ping buffer
  float Zs[32 * XLD];     // 16896 B  pong buffer (also holds z1 as [64][36])
  float rbuf[2 * H];      // readout accumulator [max(128) | mean(128)]
  float uu[N0], vv[N0], sv[N0], tv[N0], dinv[N0];
  float h1[H];
  float h2[64];
  int   sel[N0];
};

template<int NN>
__device__ __forceinline__ void compute_dinv(Shm& sh, int tid) {
  if (tid < NN) {
    float d = 1.f; // self loop
    for (int j = 0; j < NN; ++j) d += sh.adjS[tid * ALD + j];
    sh.dinv[tid] = rsqrtf(fmaxf(d, 1e-12f));
  }
}

// z[i][k] = dinv[i] * sum_j (adj[i][j] + delta_ij) * dinv[j] * x[j][k]
template<int NN, int K4>
__device__ __forceinline__ void norm_agg(const Shm& sh, const float* x, int xld,
                                         float* z, int zld, int tid) {
  for (int it = tid; it < NN * K4; it += TPB) {
    int i = it & (NN - 1);
    int g = it / NN;
    float ax = 0.f, ay = 0.f, az = 0.f, aw = 0.f;
    const float* arow = &sh.adjS[i * ALD];
    for (int j = 0; j < NN; ++j) {
      float a = (arow[j] + ((j == i) ? 1.f : 0.f)) * sh.dinv[j];
      float4 xv = *(const float4*)(x + j * xld + g * 4);
      ax += a * xv.x; ay += a * xv.y; az += a * xv.z; aw += a * xv.w;
    }
    float di = sh.dinv[i];
    float4 r = make_float4(ax * di, ay * di, az * di, aw * di);
    *(float4*)(z + i * zld + g * 4) = r;
  }
}

// out[i][f] = relu(sum_k z[i][k] * W[k][f] + b[f]), W global [KREAL][128]
template<int R, int K, int KREAL>
__device__ __forceinline__ void gemm_bias_relu(const float* z, int zld,
    const float* __restrict__ Wg, const float* __restrict__ bg,
    float* out, int old_, int tid) {
  constexpr int NR = R / 2;
  int f  = tid & (H - 1);
  int r0 = (tid >> 7) * NR;
  float acc[NR];
  float bf = bg[f];
  #pragma unroll
  for (int r = 0; r < NR; ++r) acc[r] = bf;
  #pragma unroll
  for (int kt = 0; kt < K; kt += 32) {
    const int kn = (K - kt < 32) ? (K - kt) : 32;
    float w[32];
    #pragma unroll
    for (int k = 0; k < 32; ++k)
      w[k] = (k < kn && (kt + k) < KREAL) ? Wg[(kt + k) * H + f] : 0.f;
    #pragma unroll
    for (int r = 0; r < NR; ++r) {
      const float* zr = z + (r0 + r) * zld + kt;
      float a0 = 0.f, a1 = 0.f, a2 = 0.f, a3 = 0.f;
      #pragma unroll
      for (int k = 0; k < 32; k += 4) {
        if (k < kn) {
          float4 zv = *(const float4*)(zr + k);
          a0 += zv.x * w[k];     a1 += zv.y * w[k + 1];
          a2 += zv.z * w[k + 2]; a3 += zv.w * w[k + 3];
        }
      }
      acc[r] += (a0 + a1) + (a2 + a3);
    }
  }
  #pragma unroll
  for (int r = 0; r < NR; ++r)
    out[(r0 + r) * old_ + f] = fmaxf(acc[r], 0.f);
}

// SAGPool(NN -> KK) + filtered adjacency (in place in adjS) + readout accumulate.
// x: [NN][128] stride XLD (GCN output), xn: [KK][128] stride XLD (output).
template<int NN, int KK>
__device__ __forceinline__ void sag_pool_readout(Shm& sh,
    const float* x, float* xn,
    const float* __restrict__ wl, const float* __restrict__ blp,
    const float* __restrict__ wr, int tid) {
  // u[j] = x[j]·wl, v[j] = x[j]·wr
  if (tid < 2 * NN) {
    int j = tid >> 1;
    const float* wp = (tid & 1) ? wr : wl;
    const float* xr = x + j * XLD;
    float a = 0.f;
    #pragma unroll
    for (int k = 0; k < H; k += 4) {
      float4 xv = *(const float4*)(xr + k);
      a += xv.x * wp[k] + xv.y * wp[k + 1] + xv.z * wp[k + 2] + xv.w * wp[k + 3];
    }
    if (tid & 1) sh.vv[j] = a; else sh.uu[j] = a;
  }
  __syncthreads();
  // s[i] = sum_j adj[i][j] * u[j] + bl + v[i]
  if (tid < NN) {
    float a = blp[0] + sh.vv[tid];
    const float* arow = &sh.adjS[tid * ALD];
    for (int j = 0; j < NN; ++j) a += arow[j] * sh.uu[j];
    sh.sv[tid] = a;
  }
  __syncthreads();
  // exact stable top-k via rank counting
  if (tid < NN) {
    float si = sh.sv[tid];
    int rank = 0;
    for (int j = 0; j < NN; ++j) {
      float sj = sh.sv[j];
      rank += (sj > si || (sj == si && j < tid)) ? 1 : 0;
    }
    if (rank < KK) { sh.sel[rank] = tid; sh.tv[rank] = tanhf(si); }
  }
  __syncthreads();
  // gather x_next = x[sel] * tanh(s[sel])
  for (int e = tid; e < KK * H; e += TPB) {
    int r = e >> 7, f = e & (H - 1);
    xn[r * XLD + f] = x[sh.sel[r] * XLD + f] * sh.tv[r];
  }
  // filtered adjacency: stage reads in regs, barrier, write back in place
  constexpr int NE = (KK * KK + TPB - 1) / TPB;
  float areg[NE];
  #pragma unroll
  for (int q = 0; q < NE; ++q) {
    int e = tid + q * TPB;
    if (e < KK * KK) {
      int r = e / KK, c = e & (KK - 1);
      areg[q] = sh.adjS[sh.sel[r] * ALD + sh.sel[c]];
    }
  }
  __syncthreads();
  #pragma unroll
  for (int q = 0; q < NE; ++q) {
    int e = tid + q * TPB;
    if (e < KK * KK) {
      int r = e / KK, c = e & (KK - 1);
      sh.adjS[r * ALD + c] = areg[q];
    }
  }
  // readout: cat(max, mean) over KK rows, accumulated into rbuf
  if (tid < H) {
    float m = -INFINITY, s = 0.f;
    #pragma unroll
    for (int r = 0; r < KK; ++r) {
      float v = xn[r * XLD + tid];
      m = fmaxf(m, v); s += v;
    }
    sh.rbuf[tid]     += m;
    sh.rbuf[H + tid] += s * (1.f / KK);
  }
  __syncthreads();
}

__global__ __launch_bounds__(TPB, 2) void sagpool_fused(
    const int* __restrict__ aa, const float* __restrict__ pos,
    const float* __restrict__ cdr, const float* __restrict__ adjG,
    const float* __restrict__ emb,
    const float* __restrict__ W1, const float* __restrict__ b1,
    const float* __restrict__ p1wl, const float* __restrict__ p1bl, const float* __restrict__ p1wr,
    const float* __restrict__ W2, const float* __restrict__ b2,
    const float* __restrict__ p2wl, const float* __restrict__ p2bl, const float* __restrict__ p2wr,
    const float* __restrict__ W3, const float* __restrict__ b3,
    const float* __restrict__ p3wl, const float* __restrict__ p3bl, const float* __restrict__ p3wr,
    const float* __restrict__ mW1, const float* __restrict__ mb1,
    const float* __restrict__ mW2, const float* __restrict__ mb2,
    const float* __restrict__ mW3, const float* __restrict__ mb3,
    float* __restrict__ out)
{
  __shared__ Shm sh;
  const int b   = blockIdx.x;
  const int tid = threadIdx.x;

  sh.rbuf[tid] = 0.f;

  // load adjacency [64][64] -> adjS (stride 65)
  for (int e = tid; e < (N0 * N0) / 4; e += TPB) {
    int row = e >> 4, c4 = (e & 15) * 4;
    float4 v = *(const float4*)(adjG + (size_t)b * (N0 * N0) + row * N0 + c4);
    float* dst = &sh.adjS[row * ALD + c4];
    dst[0] = v.x; dst[1] = v.y; dst[2] = v.z; dst[3] = v.w;
  }
  // build x = [emb[aa] | pos | is_cdr3 | 0 0] into Xs cols 0..35
  for (int e = tid; e < N0 * 36; e += TPB) {
    int j = e / 36, k = e - j * 36;
    int node = b * N0 + j;
    float v;
    if (k < 32)       v = emb[aa[node] * 32 + k];
    else if (k == 32) v = pos[node];
    else if (k == 33) v = cdr[node];
    else              v = 0.f;
    sh.Xs[j * XLD + k] = v;
  }
  __syncthreads();

  // ---- stage 1: GCN(34->128) on 64 nodes, pool 64->32 ----
  compute_dinv<64>(sh, tid);
  __syncthreads();
  norm_agg<64, 9>(sh, sh.Xs, XLD, sh.Zs, 36, tid);   // z1 [64][36] in Zs
  __syncthreads();
  gemm_bias_relu<64, 36, 34>(sh.Zs, 36, W1, b1, sh.Xs, XLD, tid);  // y1 -> Xs
  __syncthreads();
  sag_pool_readout<64, 32>(sh, sh.Xs, sh.Zs, p1wl, p1bl, p1wr, tid); // x2 -> Zs

  // ---- stage 2: GCN(128->128) on 32 nodes, pool 32->16 ----
  compute_dinv<32>(sh, tid);
  __syncthreads();
  norm_agg<32, 32>(sh, sh.Zs, XLD, sh.Xs, XLD, tid); // z2 -> Xs
  __syncthreads();
  gemm_bias_relu<32, 128, 128>(sh.Xs, XLD, W2, b2, sh.Zs, XLD, tid); // y2 -> Zs
  __syncthreads();
  sag_pool_readout<32, 16>(sh, sh.Zs, sh.Xs, p2wl, p2bl, p2wr, tid); // x3 -> Xs

  // ---- stage 3: GCN(128->128) on 16 nodes, pool 16->8 ----
  compute_dinv<16>(sh, tid);
  __syncthreads();
  norm_agg<16, 32>(sh, sh.Xs, XLD, sh.Zs, XLD, tid); // z3 -> Zs
  __syncthreads();
  gemm_bias_relu<16, 128, 128>(sh.Zs, XLD, W3, b3, sh.Xs, XLD, tid); // y3 -> Xs
  __syncthreads();
  sag_pool_readout<16, 8>(sh, sh.Xs, sh.Zs, p3wl, p3bl, p3wr, tid);  // x4 -> Zs

  // ---- MLP head on rbuf[256] ----
  if (tid < H) {
    float a = mb1[tid];
    for (int k = 0; k < 2 * H; ++k) a += sh.rbuf[k] * mW1[k * H + tid];
    sh.h1[tid] = fmaxf(a, 0.f);
  }
  __syncthreads();
  if (tid < 64) {
    float a = mb2[tid];
    for (int k = 0; k < H; ++k) a += sh.h1[k] * mW2[k * 64 + tid];
    sh.h2[tid] = fmaxf(a, 0.f);
  }
  __syncthreads();
  if (tid < 64) {
    sh.uu[tid] = sh.h2[tid] * mW3[tid];
  }
  __syncthreads();
  if (tid == 0) {
    float a = mb3[0];
    for (int k = 0; k < 64; ++k) a += sh.uu[k];
    out[b] = a;
  }
}

extern "C" void kernel_launch(void* const* d_in, const int* in_sizes, int n_in,
                              void* d_out, int out_size, void* d_ws, size_t ws_size,
                              hipStream_t stream) {
  (void)n_in; (void)d_ws; (void)ws_size;
  const int*   aa   = (const int*)  d_in[0];
  const float* pos  = (const float*)d_in[1];
  const float* cdr  = (const float*)d_in[2];
  const float* adj  = (const float*)d_in[3];
  const float* emb  = (const float*)d_in[4];
  const float* W1   = (const float*)d_in[5];
  const float* b1   = (const float*)d_in[6];
  const float* p1wl = (const float*)d_in[7];
  const float* p1bl = (const float*)d_in[8];
  const float* p1wr = (const float*)d_in[9];
  const float* W2   = (const float*)d_in[10];
  const float* b2   = (const float*)d_in[11];
  const float* p2wl = (const float*)d_in[12];
  const float* p2bl = (const float*)d_in[13];
  const float* p2wr = (const float*)d_in[14];
  const float* W3   = (const float*)d_in[15];
  const float* b3   = (const float*)d_in[16];
  const float* p3wl = (const float*)d_in[17];
  const float* p3bl = (const float*)d_in[18];
  const float* p3wr = (const float*)d_in[19];
  const float* mW1  = (const float*)d_in[20];
  const float* mb1  = (const float*)d_in[21];
  const float* mW2  = (const float*)d_in[22];
  const float* mb2  = (const float*)d_in[23];
  const float* mW3  = (const float*)d_in[24];
  const float* mb3  = (const float*)d_in[25];
  float* out = (float*)d_out;

  const int B = in_sizes[0] / N0;  // 4096
  (void)out_size;
  hipLaunchKernelGGL(sagpool_fused, dim3(B), dim3(TPB), 0, stream,
                     aa, pos, cdr, adj, emb,
                     W1, b1, p1wl, p1bl, p1wr,
                     W2, b2, p2wl, p2bl, p2wr,
                     W3, b3, p3wl, p3bl, p3wr,
                     mW1, mb1, mW2, mb2, mW3, mb3, out);
}